// Round 3
// baseline (24120.239 us; speedup 1.0000x reference)
//
#include <hip/hip_runtime.h>
#include <hip/hip_bf16.h>
#include <math.h>

// Problem constants
#define A_N    2000
#define P_N    20000
#define E_N    200000
#define MUL0   128
#define MUL1   64
#define DIM    320     // MUL0 + 3*MUL1
#define NBASIS 10
#define FC_HID 100
#define WNUM   384     // 128+128+64+64
#define MID0   192     // MUL0 + MUL1
#define RDIM   768     // 128 + 64 + 384 + 192
#define TILE_E 8

// scales
#define RS10   0.31622776601683794f   // 1/sqrt(10)
#define RS100  0.1f                   // 1/sqrt(100)
#define RS128  0.08838834764831845f   // 1/sqrt(128)
#define RS64   0.125f                 // 1/sqrt(64)
#define RS192  0.07216878364870323f   // 1/sqrt(192)
#define RS3    0.5773502691896258f    // 1/sqrt(3)
#define RSNEI  0.31622776601683794f   // 1/sqrt(10) neighbors

// ---------------------------------------------------------------------------
// Kernel 1: sender transform -> bf16 s0h/s1h (saves ws bytes; error ~0.2%)
// ---------------------------------------------------------------------------
__global__ __launch_bounds__(320) void sender_kernel(
    const float* __restrict__ sender_input, const float* __restrict__ sender_attr,
    const float* __restrict__ lin1_w0, const float* __restrict__ lin1_w1,
    __hip_bfloat16* __restrict__ s0h, __hip_bfloat16* __restrict__ s1h)
{
    __shared__ float sin_s[DIM];
    const int a = blockIdx.x;
    const int t = threadIdx.x;
    const float attr = sender_attr[a];
    sin_s[t] = sender_input[(size_t)a * DIM + t] * attr;
    __syncthreads();
    if (t < MUL0) {
        float acc = 0.f;
        for (int u = 0; u < MUL0; ++u)
            acc = fmaf(sin_s[u], lin1_w0[u * MUL0 + t], acc);
        s0h[(size_t)a * MUL0 + t] = __float2bfloat16(acc * RS128);
    } else {
        const int idx = t - MUL0;          // 0..191
        const int v = idx / 3, m = idx - 3 * v;
        float acc = 0.f;
        for (int u = 0; u < MUL1; ++u)
            acc = fmaf(sin_s[MUL0 + 3 * u + m], lin1_w1[u * MUL1 + v], acc);
        s1h[(size_t)a * 192 + idx] = __float2bfloat16(acc * RS64);
    }
}

// ---------------------------------------------------------------------------
// CSR build: histogram -> scan -> scatter
// ---------------------------------------------------------------------------
__global__ __launch_bounds__(256) void hist_kernel(
    const int* __restrict__ edge_dst, int* __restrict__ counts)
{
    const int e = blockIdx.x * 256 + threadIdx.x;
    if (e < E_N) atomicAdd(&counts[edge_dst[e]], 1);
}

__global__ __launch_bounds__(1024) void scan_kernel(
    const int* __restrict__ counts, int* __restrict__ head)
{
    __shared__ int part[1024];
    const int t = threadIdx.x;
    const int base = t * 20;
    int c[20];
    int s = 0;
    #pragma unroll
    for (int i = 0; i < 20; ++i) {
        const int p = base + i;
        c[i] = (p < P_N) ? counts[p] : 0;
        s += c[i];
    }
    part[t] = s;
    __syncthreads();
    for (int off = 1; off < 1024; off <<= 1) {
        const int v = (t >= off) ? part[t - off] : 0;
        __syncthreads();
        part[t] += v;
        __syncthreads();
    }
    int run = (t > 0) ? part[t - 1] : 0;   // exclusive prefix
    #pragma unroll
    for (int i = 0; i < 20; ++i) {
        const int p = base + i;
        if (p < P_N) { head[p] = run; run += c[i]; }
    }
}

__global__ __launch_bounds__(256) void scatter_kernel(
    const int* __restrict__ edge_dst, int* __restrict__ head,
    int* __restrict__ sorted)
{
    const int e = blockIdx.x * 256 + threadIdx.x;
    if (e < E_N) {
        const int pos = atomicAdd(&head[edge_dst[e]], 1);
        sorted[pos] = e;
    }
}

// ---------------------------------------------------------------------------
// Kernel 2: fused MLP + weight-GEMM + gather. One wave per receiver,
// 4 receivers/block. Per 8-edge tile: h in LDS (transposed [k][e]),
// fc_w2 staged in 20-row chunks, wacc[8][6] in registers, epilogue
// accumulates the lane's 12 r-columns. Zero fp atomics; r written once.
// ---------------------------------------------------------------------------
__global__ __launch_bounds__(256) void gather_fused_kernel(
    const int* __restrict__ sorted, const int* __restrict__ head,
    const int* __restrict__ counts,
    const int* __restrict__ edge_src, const float* __restrict__ edge_attr,
    const float* __restrict__ edge_scalars,
    const float* __restrict__ fc_w1, const float* __restrict__ fc_w2,
    const __hip_bfloat16* __restrict__ s0h, const __hip_bfloat16* __restrict__ s1h,
    float* __restrict__ r)
{
    __shared__ float fc1s[NBASIS * FC_HID];        // 4.0 KB
    __shared__ float h_s[4][FC_HID][TILE_E];       // 12.8 KB (transposed [k][e])
    __shared__ float w2s[20 * WNUM];               // 30.7 KB
    __shared__ float es_s[4][TILE_E][NBASIS];      // 1.28 KB
    __shared__ int   eid_s[4][TILE_E];             // 128 B
    __shared__ int   mt_s;

    const int tid  = threadIdx.x;
    const int wave = tid >> 6;
    const int lane = tid & 63;
    const int p = blockIdx.x * 4 + wave;

    const int cnt   = counts[p];
    const int start = head[p] - cnt;      // head = segment end after scatter

    for (int i = tid; i < NBASIS * FC_HID; i += 256) fc1s[i] = fc_w1[i];
    if (tid == 0) mt_s = 0;
    __syncthreads();                       // publishes fc1s + mt_s=0
    if (lane == 0) atomicMax(&mt_s, (cnt + TILE_E - 1) / TILE_E);
    __syncthreads();
    const int maxTiles = mt_s;

    float acc[12];
    #pragma unroll
    for (int i = 0; i < 12; ++i) acc[i] = 0.f;

    for (int t = 0; t < maxTiles; ++t) {
        const int base = t * TILE_E;

        __syncthreads();   // protect es_s/eid_s/h_s from previous tile's readers
        // stage es + eids for this wave's 8 edges
        for (int f = lane; f < TILE_E * NBASIS; f += 64) {
            const int e = f / NBASIS, i = f - e * NBASIS;
            int gi = start + base + e;
            if (gi >= E_N) gi = E_N - 1;           // harmless dummy
            const int eid = sorted[gi];
            es_s[wave][e][i] = edge_scalars[(size_t)eid * NBASIS + i];
        }
        if (lane < TILE_E) {
            const int gi = base + lane;
            eid_s[wave][lane] = (gi < cnt) ? sorted[start + gi] : -1;
        }
        __syncthreads();   // publish es_s / eid_s

        // h for 8 edges (800 values), transposed layout h_s[k][e]
        for (int f = lane; f < FC_HID * TILE_E; f += 64) {
            const int e = f & 7, k = f >> 3;
            float x = 0.f;
            #pragma unroll
            for (int i = 0; i < NBASIS; ++i)
                x = fmaf(es_s[wave][e][i], fc1s[i * FC_HID + k], x);
            x *= RS10;
            h_s[wave][k][e] = x / (1.f + __expf(-x));   // silu
        }
        // (h_s published by the first chunk barrier below)

        float wacc[TILE_E][6];
        #pragma unroll
        for (int e = 0; e < TILE_E; ++e)
            #pragma unroll
            for (int c = 0; c < 6; ++c) wacc[e][c] = 0.f;

        for (int kk = 0; kk < FC_HID; kk += 20) {
            __syncthreads();   // protect prev w2s readers; publish h_s (1st iter)
            for (int i4 = tid; i4 < (20 * WNUM) / 4; i4 += 256)
                ((float4*)w2s)[i4] =
                    ((const float4*)(fc_w2 + (size_t)kk * WNUM))[i4];
            __syncthreads();   // publish w2s
            for (int k = 0; k < 20; ++k) {
                float w[6];
                #pragma unroll
                for (int c = 0; c < 6; ++c)
                    w[c] = w2s[k * WNUM + c * 64 + lane];
                const float4 h0 = *(const float4*)&h_s[wave][kk + k][0];
                const float4 h1 = *(const float4*)&h_s[wave][kk + k][4];
                const float hv[8] = {h0.x, h0.y, h0.z, h0.w,
                                     h1.x, h1.y, h1.z, h1.w};
                #pragma unroll
                for (int e = 0; e < TILE_E; ++e)
                    #pragma unroll
                    for (int c = 0; c < 6; ++c)
                        wacc[e][c] = fmaf(hv[e], w[c], wacc[e][c]);
            }
        }

        // epilogue: apply g/sh per valid edge, accumulate lane's 12 r-columns
        #pragma unroll
        for (int e = 0; e < TILE_E; ++e) {
            const int eid = eid_s[wave][e];
            if (eid < 0) continue;
            const float sh0  = edge_attr[eid * 4 + 0];
            const float sh1x = edge_attr[eid * 4 + 1];
            const float sh1y = edge_attr[eid * 4 + 2];
            const float sh1z = edge_attr[eid * 4 + 3];
            const int src = edge_src[eid];

            const float g0a = __bfloat162float(s0h[(size_t)src * MUL0 + lane]);
            const float g0b = __bfloat162float(s0h[(size_t)src * MUL0 + 64 + lane]);
            const float g1x = __bfloat162float(s1h[(size_t)src * 192 + 3 * lane + 0]);
            const float g1y = __bfloat162float(s1h[(size_t)src * 192 + 3 * lane + 1]);
            const float g1z = __bfloat162float(s1h[(size_t)src * 192 + 3 * lane + 2]);

            const float w0a = wacc[e][0] * RS100, w0b = wacc[e][1] * RS100;
            const float w1a = wacc[e][2] * RS100, w1b = wacc[e][3] * RS100;
            const float w2v = wacc[e][4] * RS100, w3v = wacc[e][5] * RS100;

            acc[0] = fmaf(w0a * g0a, sh0, acc[0]);
            acc[1] = fmaf(w0b * g0b, sh0, acc[1]);
            const float dotg = fmaf(g1x, sh1x, fmaf(g1y, sh1y, g1z * sh1z)) * RS3;
            acc[2] = fmaf(w3v, dotg, acc[2]);
            const float p1a = w1a * g0a, p1b = w1b * g0b;
            acc[3] = fmaf(p1a, sh1x, acc[3]);
            acc[4] = fmaf(p1a, sh1y, acc[4]);
            acc[5] = fmaf(p1a, sh1z, acc[5]);
            acc[6] = fmaf(p1b, sh1x, acc[6]);
            acc[7] = fmaf(p1b, sh1y, acc[7]);
            acc[8] = fmaf(p1b, sh1z, acc[8]);
            const float q = w2v * sh0;
            acc[9]  = fmaf(q, g1x, acc[9]);
            acc[10] = fmaf(q, g1y, acc[10]);
            acc[11] = fmaf(q, g1z, acc[11]);
        }
    }

    float* rr = r + (size_t)p * RDIM;
    rr[lane]               = acc[0];
    rr[64 + lane]          = acc[1];
    rr[128 + lane]         = acc[2];
    rr[192 + 3 * lane]     = acc[3];
    rr[192 + 3 * lane + 1] = acc[4];
    rr[192 + 3 * lane + 2] = acc[5];
    rr[384 + 3 * lane]     = acc[6];
    rr[384 + 3 * lane + 1] = acc[7];
    rr[384 + 3 * lane + 2] = acc[8];
    rr[576 + 3 * lane]     = acc[9];
    rr[576 + 3 * lane + 1] = acc[10];
    rr[576 + 3 * lane + 2] = acc[11];
}

// ---------------------------------------------------------------------------
// Kernel 3: receiver finish (unchanged — validated in R1/R2)
// ---------------------------------------------------------------------------
__global__ __launch_bounds__(320) void recv_kernel(
    const float* __restrict__ receiver_input, const float* __restrict__ receiver_attr,
    const float* __restrict__ sc_w0,  const float* __restrict__ sc_w1,
    const float* __restrict__ lin2_w0, const float* __restrict__ lin2_w1,
    const float* __restrict__ lin3_w,
    const float* __restrict__ r, float* __restrict__ out)
{
    __shared__ float rin_s[8 * DIM];
    __shared__ float rr_s[8 * RDIM];
    __shared__ float cos_s[8], sin_s[8];

    const int tid = threadIdx.x;
    const int pbase = blockIdx.x * 8;

    for (int i = tid; i < 8 * DIM; i += 320) {
        const int p = i / DIM;
        rin_s[i] = receiver_input[(size_t)pbase * DIM + i] * receiver_attr[pbase + p];
    }
    for (int i = tid; i < 8 * RDIM; i += 320) {
        const int p = i / RDIM;
        rr_s[i] = r[(size_t)pbase * RDIM + i] * RSNEI * receiver_attr[pbase + p];
    }
    __syncthreads();

    if (tid < 64) {
        const int p = tid >> 3, i0 = tid & 7;
        float a = 0.f;
        for (int u = i0; u < MID0; u += 8)
            a = fmaf(rr_s[p * RDIM + u], lin3_w[u], a);
        a += __shfl_xor(a, 1);
        a += __shfl_xor(a, 2);
        a += __shfl_xor(a, 4);
        if (i0 == 0) {
            a *= 0.1f * RS192;
            cos_s[p] = __cosf(a);
            sin_s[p] = __sinf(a);
        }
    }
    __syncthreads();

    if (tid < MUL0) {
        const int j = tid;
        float asc[8], acv[8];
        #pragma unroll
        for (int p = 0; p < 8; ++p) { asc[p] = 0.f; acv[p] = 0.f; }
        for (int u = 0; u < MUL0; ++u) {
            const float w = sc_w0[u * MUL0 + j];
            #pragma unroll
            for (int p = 0; p < 8; ++p) asc[p] = fmaf(rin_s[p * DIM + u], w, asc[p]);
        }
        for (int u = 0; u < MID0; ++u) {
            const float w = lin2_w0[u * MUL0 + j];
            #pragma unroll
            for (int p = 0; p < 8; ++p) acv[p] = fmaf(rr_s[p * RDIM + u], w, acv[p]);
        }
        #pragma unroll
        for (int p = 0; p < 8; ++p)
            out[(size_t)(pbase + p) * DIM + j] =
                cos_s[p] * asc[p] * RS128 + sin_s[p] * acv[p] * RS192;
    } else {
        const int idx = tid - MUL0;
        const int v = idx / 3, m = idx - 3 * v;
        float asc[8], acv[8];
        #pragma unroll
        for (int p = 0; p < 8; ++p) { asc[p] = 0.f; acv[p] = 0.f; }
        for (int u = 0; u < MUL1; ++u) {
            const float w = sc_w1[u * MUL1 + v];
            #pragma unroll
            for (int p = 0; p < 8; ++p)
                asc[p] = fmaf(rin_s[p * DIM + MUL0 + 3 * u + m], w, asc[p]);
        }
        for (int u = 0; u < MID0; ++u) {
            const float w = lin2_w1[u * MUL1 + v];
            #pragma unroll
            for (int p = 0; p < 8; ++p)
                acv[p] = fmaf(rr_s[p * RDIM + 192 + 3 * u + m], w, acv[p]);
        }
        #pragma unroll
        for (int p = 0; p < 8; ++p)
            out[(size_t)(pbase + p) * DIM + MUL0 + idx] =
                cos_s[p] * asc[p] * RS64 + sin_s[p] * acv[p] * RS192;
    }
}

// ---------------------------------------------------------------------------
extern "C" void kernel_launch(void* const* d_in, const int* in_sizes, int n_in,
                              void* d_out, int out_size, void* d_ws, size_t ws_size,
                              hipStream_t stream)
{
    const float* sender_input   = (const float*)d_in[0];
    const float* sender_attr    = (const float*)d_in[1];
    const float* receiver_input = (const float*)d_in[2];
    const float* receiver_attr  = (const float*)d_in[3];
    const int*   edge_src       = (const int*)  d_in[4];
    const int*   edge_dst       = (const int*)  d_in[5];
    const float* edge_attr      = (const float*)d_in[6];
    const float* edge_scalars   = (const float*)d_in[7];
    const float* fc_w1          = (const float*)d_in[8];
    const float* fc_w2          = (const float*)d_in[9];
    const float* lin1_w0        = (const float*)d_in[10];
    const float* lin1_w1        = (const float*)d_in[11];
    const float* sc_w0          = (const float*)d_in[12];
    const float* sc_w1          = (const float*)d_in[13];
    const float* lin2_w0        = (const float*)d_in[14];
    const float* lin2_w1        = (const float*)d_in[15];
    const float* lin3_w         = (const float*)d_in[16];
    float* out = (float*)d_out;

    // ws layout (63.68 MB total, fits the proven >= 64 MB):
    // r [P,768] f32 | s0h [A,128] bf16 | s1h [A,192] bf16 |
    // counts [P] | head [P] | sorted [E]
    float* r = (float*)d_ws;
    __hip_bfloat16* s0h = (__hip_bfloat16*)(r + (size_t)P_N * RDIM);
    __hip_bfloat16* s1h = s0h + (size_t)A_N * MUL0;
    int* counts = (int*)(s1h + (size_t)A_N * 192);
    int* head   = counts + P_N;
    int* sorted = head + P_N;

    sender_kernel<<<A_N, 320, 0, stream>>>(sender_input, sender_attr,
                                           lin1_w0, lin1_w1, s0h, s1h);
    hipMemsetAsync(counts, 0, P_N * sizeof(int), stream);
    hist_kernel<<<(E_N + 255) / 256, 256, 0, stream>>>(edge_dst, counts);
    scan_kernel<<<1, 1024, 0, stream>>>(counts, head);
    scatter_kernel<<<(E_N + 255) / 256, 256, 0, stream>>>(edge_dst, head, sorted);
    gather_fused_kernel<<<P_N / 4, 256, 0, stream>>>(
        sorted, head, counts, edge_src, edge_attr, edge_scalars,
        fc_w1, fc_w2, s0h, s1h, r);
    recv_kernel<<<P_N / 8, 320, 0, stream>>>(receiver_input, receiver_attr,
                                             sc_w0, sc_w1, lin2_w0, lin2_w1,
                                             lin3_w, r, out);
}

// Round 4
// 2715.594 us; speedup vs baseline: 8.8821x; 8.8821x over previous
//
#include <hip/hip_runtime.h>
#include <hip/hip_bf16.h>
#include <math.h>

// Problem constants
#define A_N    2000
#define P_N    20000
#define E_N    200000
#define MUL0   128
#define MUL1   64
#define DIM    320     // MUL0 + 3*MUL1
#define NBASIS 10
#define FC_HID 100
#define WNUM   384     // 128+128+64+64
#define MID0   192     // MUL0 + MUL1
#define RDIM   768     // 128 + 64 + 384 + 192

// chunking of the sorted edge list
#define C_CHUNK 40000
#define OV      128            // > max edges per receiver (Poisson(10) max ~30)
#define NCHUNK  5

// scales
#define RS10   0.31622776601683794f   // 1/sqrt(10)
#define RS100  0.1f                   // 1/sqrt(100)
#define RS128  0.08838834764831845f   // 1/sqrt(128)
#define RS64   0.125f                 // 1/sqrt(64)
#define RS192  0.07216878364870323f   // 1/sqrt(192)
#define RS3    0.5773502691896258f    // 1/sqrt(3)
#define RSNEI  0.31622776601683794f   // 1/sqrt(10) neighbors

// ---------------------------------------------------------------------------
// Kernel 1: sender transform -> bf16 s0h/s1h (proven R3; error contribution
// ~0.2%, absmax 0.031 vs threshold 0.11)
// ---------------------------------------------------------------------------
__global__ __launch_bounds__(320) void sender_kernel(
    const float* __restrict__ sender_input, const float* __restrict__ sender_attr,
    const float* __restrict__ lin1_w0, const float* __restrict__ lin1_w1,
    __hip_bfloat16* __restrict__ s0h, __hip_bfloat16* __restrict__ s1h)
{
    __shared__ float sin_s[DIM];
    const int a = blockIdx.x;
    const int t = threadIdx.x;
    const float attr = sender_attr[a];
    sin_s[t] = sender_input[(size_t)a * DIM + t] * attr;
    __syncthreads();
    if (t < MUL0) {
        float acc = 0.f;
        for (int u = 0; u < MUL0; ++u)
            acc = fmaf(sin_s[u], lin1_w0[u * MUL0 + t], acc);
        s0h[(size_t)a * MUL0 + t] = __float2bfloat16(acc * RS128);
    } else {
        const int idx = t - MUL0;          // 0..191
        const int v = idx / 3, m = idx - 3 * v;
        float acc = 0.f;
        for (int u = 0; u < MUL1; ++u)
            acc = fmaf(sin_s[MUL0 + 3 * u + m], lin1_w1[u * MUL1 + v], acc);
        s1h[(size_t)a * 192 + idx] = __float2bfloat16(acc * RS64);
    }
}

// ---------------------------------------------------------------------------
// CSR build: histogram -> scan -> scatter   (proven R3)
// ---------------------------------------------------------------------------
__global__ __launch_bounds__(256) void hist_kernel(
    const int* __restrict__ edge_dst, int* __restrict__ counts)
{
    const int e = blockIdx.x * 256 + threadIdx.x;
    if (e < E_N) atomicAdd(&counts[edge_dst[e]], 1);
}

__global__ __launch_bounds__(1024) void scan_kernel(
    const int* __restrict__ counts, int* __restrict__ head)
{
    __shared__ int part[1024];
    const int t = threadIdx.x;
    const int base = t * 20;
    int c[20];
    int s = 0;
    #pragma unroll
    for (int i = 0; i < 20; ++i) {
        const int p = base + i;
        c[i] = (p < P_N) ? counts[p] : 0;
        s += c[i];
    }
    part[t] = s;
    __syncthreads();
    for (int off = 1; off < 1024; off <<= 1) {
        const int v = (t >= off) ? part[t - off] : 0;
        __syncthreads();
        part[t] += v;
        __syncthreads();
    }
    int run = (t > 0) ? part[t - 1] : 0;   // exclusive prefix
    #pragma unroll
    for (int i = 0; i < 20; ++i) {
        const int p = base + i;
        if (p < P_N) { head[p] = run; run += c[i]; }
    }
}

__global__ __launch_bounds__(256) void scatter_kernel(
    const int* __restrict__ edge_dst, int* __restrict__ head,
    int* __restrict__ sorted)
{
    const int e = blockIdx.x * 256 + threadIdx.x;
    if (e < E_N) {
        const int pos = atomicAdd(&head[edge_dst[e]], 1);
        sorted[pos] = e;
    }
}

// ---------------------------------------------------------------------------
// Kernel A: MLP + weight GEMM over one chunk of the SORTED edge list.
// R1's proven 32-edge-block structure; writes wbuf[pos-cLo] with RS100 folded.
// nPos is always a multiple of 32 (40128 or 40000) -> no tail guards.
// ---------------------------------------------------------------------------
__global__ __launch_bounds__(256) void mlp_gemm_chunk_kernel(
    const int* __restrict__ sorted,
    const float* __restrict__ edge_scalars,
    const float* __restrict__ fc_w1, const float* __restrict__ fc_w2,
    float* __restrict__ wbuf, int cLo)
{
    __shared__ float fc1s[NBASIS * FC_HID];   // 4 KB
    __shared__ float es_s[32 * NBASIS];       // 1.3 KB
    __shared__ float h_s[32 * FC_HID];        // 12.8 KB
    __shared__ float w2s[20 * WNUM];          // 30.7 KB
    __shared__ int   eid_s[32];

    const int tid  = threadIdx.x;
    const int wave = tid >> 6;
    const int lane = tid & 63;
    const int pbase = blockIdx.x * 32;        // position within chunk

    if (tid < 32) eid_s[tid] = sorted[cLo + pbase + tid];
    for (int i = tid; i < NBASIS * FC_HID; i += 256) fc1s[i] = fc_w1[i];
    __syncthreads();

    for (int f = tid; f < 32 * NBASIS; f += 256) {
        const int e = f / NBASIS, i = f - e * NBASIS;
        es_s[f] = edge_scalars[(size_t)eid_s[e] * NBASIS + i];
    }
    __syncthreads();

    for (int idx = tid; idx < 32 * FC_HID; idx += 256) {
        const int e = idx / FC_HID, k = idx - e * FC_HID;
        float x = 0.f;
        #pragma unroll
        for (int i = 0; i < NBASIS; ++i)
            x = fmaf(es_s[e * NBASIS + i], fc1s[i * FC_HID + k], x);
        x *= RS10;
        h_s[idx] = x / (1.f + __expf(-x));    // silu
    }

    float acc[8][6];
    #pragma unroll
    for (int e = 0; e < 8; ++e)
        #pragma unroll
        for (int c = 0; c < 6; ++c) acc[e][c] = 0.f;

    for (int kk = 0; kk < FC_HID; kk += 20) {
        __syncthreads();
        for (int i4 = tid; i4 < (20 * WNUM) / 4; i4 += 256)
            ((float4*)w2s)[i4] = ((const float4*)(fc_w2 + (size_t)kk * WNUM))[i4];
        __syncthreads();
        for (int k = 0; k < 20; ++k) {
            float w[6];
            #pragma unroll
            for (int c = 0; c < 6; ++c) w[c] = w2s[k * WNUM + c * 64 + lane];
            #pragma unroll
            for (int e = 0; e < 8; ++e) {
                const float hv = h_s[(wave * 8 + e) * FC_HID + kk + k];
                #pragma unroll
                for (int c = 0; c < 6; ++c) acc[e][c] = fmaf(hv, w[c], acc[e][c]);
            }
        }
    }

    const int mypos = pbase + wave * 8;
    #pragma unroll
    for (int e = 0; e < 8; ++e) {
        float* wr = wbuf + (size_t)(mypos + e) * WNUM;
        #pragma unroll
        for (int c = 0; c < 6; ++c)
            wr[c * 64 + lane] = acc[e][c] * RS100;
    }
}

// ---------------------------------------------------------------------------
// Kernel B: gather + receiver finish, fused. 4 waves/block, 1 receiver/wave.
// Processes only receivers whose segment START lies in [cLo, cHi); the 128-
// edge overlap in wbuf guarantees the whole segment is resident.
// r row lives only in LDS. Zero fp atomics.
// ---------------------------------------------------------------------------
__global__ __launch_bounds__(256) void recv_gather_kernel(
    const int* __restrict__ sorted, const int* __restrict__ head,
    const int* __restrict__ counts,
    const int* __restrict__ edge_src, const float* __restrict__ edge_attr,
    const float* __restrict__ wbuf,
    const __hip_bfloat16* __restrict__ s0h, const __hip_bfloat16* __restrict__ s1h,
    const float* __restrict__ receiver_input, const float* __restrict__ receiver_attr,
    const float* __restrict__ sc_w0,  const float* __restrict__ sc_w1,
    const float* __restrict__ lin2_w0, const float* __restrict__ lin2_w1,
    const float* __restrict__ lin3_w,
    float* __restrict__ out, int cLo, int cHi)
{
    __shared__ float rr_s[4][RDIM];    // 12 KB   (scaled r rows)
    __shared__ float rin_s[4][DIM];    // 5 KB
    __shared__ float cs_s[4], sn_s[4];
    __shared__ int   sel_s[4];

    const int tid  = threadIdx.x;
    const int wave = tid >> 6;
    const int lane = tid & 63;
    const int p = blockIdx.x * 4 + wave;

    const int cnt   = counts[p];
    const int start = head[p] - cnt;               // head = segment end
    const int sel   = (start >= cLo) & (start < cHi);

    if (lane == 0) sel_s[wave] = sel;
    __syncthreads();
    if ((sel_s[0] | sel_s[1] | sel_s[2] | sel_s[3]) == 0) return;  // uniform

    const int cntEff = sel ? cnt : 0;

    float acc[12];
    #pragma unroll
    for (int i = 0; i < 12; ++i) acc[i] = 0.f;

    for (int i = 0; i < cntEff; ++i) {
        const int pos = start + i;
        const int eid = sorted[pos];
        const float* wr = wbuf + (size_t)(pos - cLo) * WNUM;
        const float w0a = wr[lane],       w0b = wr[64 + lane];
        const float w1a = wr[128 + lane], w1b = wr[192 + lane];
        const float w2v = wr[256 + lane], w3v = wr[320 + lane];

        const int src = edge_src[eid];
        const float4 ea = ((const float4*)edge_attr)[eid];
        const float sh0 = ea.x, sh1x = ea.y, sh1y = ea.z, sh1z = ea.w;

        const float g0a = __bfloat162float(s0h[(size_t)src * MUL0 + lane]);
        const float g0b = __bfloat162float(s0h[(size_t)src * MUL0 + 64 + lane]);
        const float g1x = __bfloat162float(s1h[(size_t)src * 192 + 3 * lane + 0]);
        const float g1y = __bfloat162float(s1h[(size_t)src * 192 + 3 * lane + 1]);
        const float g1z = __bfloat162float(s1h[(size_t)src * 192 + 3 * lane + 2]);

        acc[0] = fmaf(w0a * g0a, sh0, acc[0]);
        acc[1] = fmaf(w0b * g0b, sh0, acc[1]);
        const float dotg = fmaf(g1x, sh1x, fmaf(g1y, sh1y, g1z * sh1z)) * RS3;
        acc[2] = fmaf(w3v, dotg, acc[2]);
        const float p1a = w1a * g0a, p1b = w1b * g0b;
        acc[3] = fmaf(p1a, sh1x, acc[3]);
        acc[4] = fmaf(p1a, sh1y, acc[4]);
        acc[5] = fmaf(p1a, sh1z, acc[5]);
        acc[6] = fmaf(p1b, sh1x, acc[6]);
        acc[7] = fmaf(p1b, sh1y, acc[7]);
        acc[8] = fmaf(p1b, sh1z, acc[8]);
        const float q = w2v * sh0;
        acc[9]  = fmaf(q, g1x, acc[9]);
        acc[10] = fmaf(q, g1y, acc[10]);
        acc[11] = fmaf(q, g1z, acc[11]);
    }

    // stage scaled r row + scaled receiver_input into LDS
    const float rattr = receiver_attr[p];
    const float rfac  = RSNEI * rattr;
    rr_s[wave][lane]               = acc[0]  * rfac;
    rr_s[wave][64 + lane]          = acc[1]  * rfac;
    rr_s[wave][128 + lane]         = acc[2]  * rfac;
    rr_s[wave][192 + 3 * lane]     = acc[3]  * rfac;
    rr_s[wave][192 + 3 * lane + 1] = acc[4]  * rfac;
    rr_s[wave][192 + 3 * lane + 2] = acc[5]  * rfac;
    rr_s[wave][384 + 3 * lane]     = acc[6]  * rfac;
    rr_s[wave][384 + 3 * lane + 1] = acc[7]  * rfac;
    rr_s[wave][384 + 3 * lane + 2] = acc[8]  * rfac;
    rr_s[wave][576 + 3 * lane]     = acc[9]  * rfac;
    rr_s[wave][576 + 3 * lane + 1] = acc[10] * rfac;
    rr_s[wave][576 + 3 * lane + 2] = acc[11] * rfac;
    for (int jj = lane; jj < DIM; jj += 64)
        rin_s[wave][jj] = receiver_input[(size_t)p * DIM + jj] * rattr;
    __syncthreads();

    // angle per receiver (8 lanes each, all in wave 0)
    if (tid < 32) {
        const int pw = tid >> 3, i0 = tid & 7;
        float a = 0.f;
        for (int u = i0; u < MID0; u += 8)
            a = fmaf(rr_s[pw][u], lin3_w[u], a);
        a += __shfl_xor(a, 1);
        a += __shfl_xor(a, 2);
        a += __shfl_xor(a, 4);
        if (i0 == 0) {
            a *= 0.1f * RS192;
            cs_s[pw] = __cosf(a);
            sn_s[pw] = __sinf(a);
        }
    }
    __syncthreads();

    // output: 320 columns x 4 receivers, weights reused across the 4
    for (int jj = tid; jj < DIM; jj += 256) {
        float asc[4] = {0.f, 0.f, 0.f, 0.f};
        float acv[4] = {0.f, 0.f, 0.f, 0.f};
        if (jj < MUL0) {
            for (int u = 0; u < MUL0; ++u) {
                const float w = sc_w0[u * MUL0 + jj];
                #pragma unroll
                for (int pp = 0; pp < 4; ++pp)
                    asc[pp] = fmaf(rin_s[pp][u], w, asc[pp]);
            }
            for (int u = 0; u < MID0; ++u) {
                const float w = lin2_w0[u * MUL0 + jj];
                #pragma unroll
                for (int pp = 0; pp < 4; ++pp)
                    acv[pp] = fmaf(rr_s[pp][u], w, acv[pp]);
            }
            #pragma unroll
            for (int pp = 0; pp < 4; ++pp)
                if (sel_s[pp])
                    out[(size_t)(blockIdx.x * 4 + pp) * DIM + jj] =
                        cs_s[pp] * asc[pp] * RS128 + sn_s[pp] * acv[pp] * RS192;
        } else {
            const int idx = jj - MUL0;
            const int v = idx / 3, m = idx - 3 * v;
            for (int u = 0; u < MUL1; ++u) {
                const float w = sc_w1[u * MUL1 + v];
                #pragma unroll
                for (int pp = 0; pp < 4; ++pp)
                    asc[pp] = fmaf(rin_s[pp][MUL0 + 3 * u + m], w, asc[pp]);
            }
            for (int u = 0; u < MID0; ++u) {
                const float w = lin2_w1[u * MUL1 + v];
                #pragma unroll
                for (int pp = 0; pp < 4; ++pp)
                    acv[pp] = fmaf(rr_s[pp][192 + 3 * u + m], w, acv[pp]);
            }
            #pragma unroll
            for (int pp = 0; pp < 4; ++pp)
                if (sel_s[pp])
                    out[(size_t)(blockIdx.x * 4 + pp) * DIM + jj] =
                        cs_s[pp] * asc[pp] * RS64 + sn_s[pp] * acv[pp] * RS192;
        }
    }
}

// ---------------------------------------------------------------------------
extern "C" void kernel_launch(void* const* d_in, const int* in_sizes, int n_in,
                              void* d_out, int out_size, void* d_ws, size_t ws_size,
                              hipStream_t stream)
{
    const float* sender_input   = (const float*)d_in[0];
    const float* sender_attr    = (const float*)d_in[1];
    const float* receiver_input = (const float*)d_in[2];
    const float* receiver_attr  = (const float*)d_in[3];
    const int*   edge_src       = (const int*)  d_in[4];
    const int*   edge_dst       = (const int*)  d_in[5];
    const float* edge_attr      = (const float*)d_in[6];
    const float* edge_scalars   = (const float*)d_in[7];
    const float* fc_w1          = (const float*)d_in[8];
    const float* fc_w2          = (const float*)d_in[9];
    const float* lin1_w0        = (const float*)d_in[10];
    const float* lin1_w1        = (const float*)d_in[11];
    const float* sc_w0          = (const float*)d_in[12];
    const float* sc_w1          = (const float*)d_in[13];
    const float* lin2_w0        = (const float*)d_in[14];
    const float* lin2_w1        = (const float*)d_in[15];
    const float* lin3_w         = (const float*)d_in[16];
    float* out = (float*)d_out;

    // ws layout (63.88 MB total, fits the R1-proven >= 64.0 MB):
    // wbuf [(C+OV)*384] f32 | s0h [A*128] bf16 | s1h [A*192] bf16 |
    // counts [P] | head [P] | sorted [E]
    float* wbuf = (float*)d_ws;
    __hip_bfloat16* s0h = (__hip_bfloat16*)(wbuf + (size_t)(C_CHUNK + OV) * WNUM);
    __hip_bfloat16* s1h = s0h + (size_t)A_N * MUL0;
    int* counts = (int*)(s1h + (size_t)A_N * 192);
    int* head   = counts + P_N;
    int* sorted = head + P_N;

    sender_kernel<<<A_N, 320, 0, stream>>>(sender_input, sender_attr,
                                           lin1_w0, lin1_w1, s0h, s1h);
    hipMemsetAsync(counts, 0, P_N * sizeof(int), stream);
    hist_kernel<<<(E_N + 255) / 256, 256, 0, stream>>>(edge_dst, counts);
    scan_kernel<<<1, 1024, 0, stream>>>(counts, head);
    scatter_kernel<<<(E_N + 255) / 256, 256, 0, stream>>>(edge_dst, head, sorted);

    for (int c = 0; c < NCHUNK; ++c) {
        const int cLo  = c * C_CHUNK;
        const int nPos = (E_N - cLo < C_CHUNK + OV) ? (E_N - cLo) : (C_CHUNK + OV);
        const int cHi  = (c == NCHUNK - 1) ? (E_N + 1) : (cLo + C_CHUNK);
        mlp_gemm_chunk_kernel<<<nPos / 32, 256, 0, stream>>>(
            sorted, edge_scalars, fc_w1, fc_w2, wbuf, cLo);
        recv_gather_kernel<<<P_N / 4, 256, 0, stream>>>(
            sorted, head, counts, edge_src, edge_attr, wbuf, s0h, s1h,
            receiver_input, receiver_attr, sc_w0, sc_w1, lin2_w0, lin2_w1,
            lin3_w, out, cLo, cHi);
    }
}

// Round 5
// 561.490 us; speedup vs baseline: 42.9576x; 4.8364x over previous
//
#include <hip/hip_runtime.h>
#include <hip/hip_bf16.h>
#include <math.h>

// Problem constants
#define A_N    2000
#define P_N    20000
#define E_N    200000
#define MUL0   128
#define MUL1   64
#define DIM    320     // MUL0 + 3*MUL1
#define NBASIS 10
#define FC_HID 100
#define WNUM   384     // 128+128+64+64
#define MID0   192     // MUL0 + MUL1
#define RDIM   768     // 128 + 64 + 384 + 192

// chunking of the sorted edge list (wbuf is bf16 now -> 3 chunks)
#define C_CHUNK 66688
#define OV      128            // > max edges per receiver (Poisson(10) max ~30)
#define NCHUNK  3

// scales
#define RS10   0.31622776601683794f   // 1/sqrt(10)
#define RS100  0.1f                   // 1/sqrt(100)
#define RS128  0.08838834764831845f   // 1/sqrt(128)
#define RS64   0.125f                 // 1/sqrt(64)
#define RS192  0.07216878364870323f   // 1/sqrt(192)
#define RS3    0.5773502691896258f    // 1/sqrt(3)
#define RSNEI  0.31622776601683794f   // 1/sqrt(10) neighbors

// ---------------------------------------------------------------------------
// Kernel 1: sender transform -> bf16 s0h/s1h (proven R3/R4)
// ---------------------------------------------------------------------------
__global__ __launch_bounds__(320) void sender_kernel(
    const float* __restrict__ sender_input, const float* __restrict__ sender_attr,
    const float* __restrict__ lin1_w0, const float* __restrict__ lin1_w1,
    __hip_bfloat16* __restrict__ s0h, __hip_bfloat16* __restrict__ s1h)
{
    __shared__ float sin_s[DIM];
    const int a = blockIdx.x;
    const int t = threadIdx.x;
    const float attr = sender_attr[a];
    sin_s[t] = sender_input[(size_t)a * DIM + t] * attr;
    __syncthreads();
    if (t < MUL0) {
        float acc = 0.f;
        for (int u = 0; u < MUL0; ++u)
            acc = fmaf(sin_s[u], lin1_w0[u * MUL0 + t], acc);
        s0h[(size_t)a * MUL0 + t] = __float2bfloat16(acc * RS128);
    } else {
        const int idx = t - MUL0;          // 0..191
        const int v = idx / 3, m = idx - 3 * v;
        float acc = 0.f;
        for (int u = 0; u < MUL1; ++u)
            acc = fmaf(sin_s[MUL0 + 3 * u + m], lin1_w1[u * MUL1 + v], acc);
        s1h[(size_t)a * 192 + idx] = __float2bfloat16(acc * RS64);
    }
}

// ---------------------------------------------------------------------------
// CSR build: histogram -> scan -> scatter   (proven R3/R4)
// ---------------------------------------------------------------------------
__global__ __launch_bounds__(256) void hist_kernel(
    const int* __restrict__ edge_dst, int* __restrict__ counts)
{
    const int e = blockIdx.x * 256 + threadIdx.x;
    if (e < E_N) atomicAdd(&counts[edge_dst[e]], 1);
}

__global__ __launch_bounds__(1024) void scan_kernel(
    const int* __restrict__ counts, int* __restrict__ head)
{
    __shared__ int part[1024];
    const int t = threadIdx.x;
    const int base = t * 20;
    int c[20];
    int s = 0;
    #pragma unroll
    for (int i = 0; i < 20; ++i) {
        const int p = base + i;
        c[i] = (p < P_N) ? counts[p] : 0;
        s += c[i];
    }
    part[t] = s;
    __syncthreads();
    for (int off = 1; off < 1024; off <<= 1) {
        const int v = (t >= off) ? part[t - off] : 0;
        __syncthreads();
        part[t] += v;
        __syncthreads();
    }
    int run = (t > 0) ? part[t - 1] : 0;   // exclusive prefix
    #pragma unroll
    for (int i = 0; i < 20; ++i) {
        const int p = base + i;
        if (p < P_N) { head[p] = run; run += c[i]; }
    }
}

__global__ __launch_bounds__(256) void scatter_kernel(
    const int* __restrict__ edge_dst, int* __restrict__ head,
    int* __restrict__ sorted)
{
    const int e = blockIdx.x * 256 + threadIdx.x;
    if (e < E_N) {
        const int pos = atomicAdd(&head[edge_dst[e]], 1);
        sorted[pos] = e;
    }
}

// ---------------------------------------------------------------------------
// Kernel A (rewritten, register-light): MLP + weight GEMM over one chunk of
// the SORTED edge list. 384 threads, 32 edges/block. Thread tid owns output
// column tid for all 32 edges: acc[32] (~80 VGPR, no spill). Per k: one
// coalesced fc_w2 read (L2-resident) + 8 broadcast float4 LDS reads of
// h_s[k][*] + 32 FMAs. RS100 folded into the bf16 store.
// ---------------------------------------------------------------------------
__global__ __launch_bounds__(384) void mlp_gemm_chunk_kernel(
    const int* __restrict__ sorted,
    const float* __restrict__ edge_scalars,
    const float* __restrict__ fc_w1, const float* __restrict__ fc_w2,
    __hip_bfloat16* __restrict__ wbuf, int cLo)
{
    __shared__ float fc1s[NBASIS * FC_HID];   // 4 KB
    __shared__ float es_s[32 * NBASIS];       // 1.25 KB
    __shared__ float h_s[FC_HID][32];         // 12.8 KB, transposed [k][e]
    __shared__ int   eid_s[32];

    const int tid   = threadIdx.x;
    const int pbase = blockIdx.x * 32;        // position within chunk

    if (tid < 32) eid_s[tid] = sorted[cLo + pbase + tid];
    for (int i = tid; i < NBASIS * FC_HID; i += 384) fc1s[i] = fc_w1[i];
    __syncthreads();

    for (int f = tid; f < 32 * NBASIS; f += 384) {
        const int e = f / NBASIS, i = f - e * NBASIS;
        es_s[f] = edge_scalars[(size_t)eid_s[e] * NBASIS + i];
    }
    __syncthreads();

    // h: 3200 values, consecutive threads -> consecutive addresses
    for (int idx = tid; idx < FC_HID * 32; idx += 384) {
        const int e = idx & 31, k = idx >> 5;
        float x = 0.f;
        #pragma unroll
        for (int i = 0; i < NBASIS; ++i)
            x = fmaf(es_s[e * NBASIS + i], fc1s[i * FC_HID + k], x);
        x *= RS10;
        h_s[k][e] = x / (1.f + __expf(-x));   // silu
    }
    __syncthreads();

    float acc[32];
    #pragma unroll
    for (int e = 0; e < 32; ++e) acc[e] = 0.f;

    const float* w2col = fc_w2 + tid;
    #pragma unroll 2
    for (int k = 0; k < FC_HID; ++k) {
        const float w = w2col[(size_t)k * WNUM];       // coalesced, L2-hit
        const float4 h0 = *(const float4*)&h_s[k][0];  // broadcast reads
        const float4 h1 = *(const float4*)&h_s[k][4];
        const float4 h2 = *(const float4*)&h_s[k][8];
        const float4 h3 = *(const float4*)&h_s[k][12];
        const float4 h4 = *(const float4*)&h_s[k][16];
        const float4 h5 = *(const float4*)&h_s[k][20];
        const float4 h6 = *(const float4*)&h_s[k][24];
        const float4 h7 = *(const float4*)&h_s[k][28];
        const float hv[32] = {h0.x,h0.y,h0.z,h0.w, h1.x,h1.y,h1.z,h1.w,
                              h2.x,h2.y,h2.z,h2.w, h3.x,h3.y,h3.z,h3.w,
                              h4.x,h4.y,h4.z,h4.w, h5.x,h5.y,h5.z,h5.w,
                              h6.x,h6.y,h6.z,h6.w, h7.x,h7.y,h7.z,h7.w};
        #pragma unroll
        for (int e = 0; e < 32; ++e)
            acc[e] = fmaf(hv[e], w, acc[e]);
    }

    __hip_bfloat16* wr = wbuf + (size_t)pbase * WNUM + tid;
    #pragma unroll
    for (int e = 0; e < 32; ++e)
        wr[(size_t)e * WNUM] = __float2bfloat16(acc[e] * RS100);
}

// ---------------------------------------------------------------------------
// Kernel B: gather + receiver finish, fused (proven R4; wbuf now bf16).
// ---------------------------------------------------------------------------
__global__ __launch_bounds__(256) void recv_gather_kernel(
    const int* __restrict__ sorted, const int* __restrict__ head,
    const int* __restrict__ counts,
    const int* __restrict__ edge_src, const float* __restrict__ edge_attr,
    const __hip_bfloat16* __restrict__ wbuf,
    const __hip_bfloat16* __restrict__ s0h, const __hip_bfloat16* __restrict__ s1h,
    const float* __restrict__ receiver_input, const float* __restrict__ receiver_attr,
    const float* __restrict__ sc_w0,  const float* __restrict__ sc_w1,
    const float* __restrict__ lin2_w0, const float* __restrict__ lin2_w1,
    const float* __restrict__ lin3_w,
    float* __restrict__ out, int cLo, int cHi)
{
    __shared__ float rr_s[4][RDIM];    // 12 KB   (scaled r rows)
    __shared__ float rin_s[4][DIM];    // 5 KB
    __shared__ float cs_s[4], sn_s[4];
    __shared__ int   sel_s[4];

    const int tid  = threadIdx.x;
    const int wave = tid >> 6;
    const int lane = tid & 63;
    const int p = blockIdx.x * 4 + wave;

    const int cnt   = counts[p];
    const int start = head[p] - cnt;               // head = segment end
    const int sel   = (start >= cLo) & (start < cHi);

    if (lane == 0) sel_s[wave] = sel;
    __syncthreads();
    if ((sel_s[0] | sel_s[1] | sel_s[2] | sel_s[3]) == 0) return;  // uniform

    const int cntEff = sel ? cnt : 0;

    float acc[12];
    #pragma unroll
    for (int i = 0; i < 12; ++i) acc[i] = 0.f;

    for (int i = 0; i < cntEff; ++i) {
        const int pos = start + i;
        const int eid = sorted[pos];
        const __hip_bfloat16* wr = wbuf + (size_t)(pos - cLo) * WNUM;
        const float w0a = __bfloat162float(wr[lane]);
        const float w0b = __bfloat162float(wr[64 + lane]);
        const float w1a = __bfloat162float(wr[128 + lane]);
        const float w1b = __bfloat162float(wr[192 + lane]);
        const float w2v = __bfloat162float(wr[256 + lane]);
        const float w3v = __bfloat162float(wr[320 + lane]);

        const int src = edge_src[eid];
        const float4 ea = ((const float4*)edge_attr)[eid];
        const float sh0 = ea.x, sh1x = ea.y, sh1y = ea.z, sh1z = ea.w;

        const float g0a = __bfloat162float(s0h[(size_t)src * MUL0 + lane]);
        const float g0b = __bfloat162float(s0h[(size_t)src * MUL0 + 64 + lane]);
        const float g1x = __bfloat162float(s1h[(size_t)src * 192 + 3 * lane + 0]);
        const float g1y = __bfloat162float(s1h[(size_t)src * 192 + 3 * lane + 1]);
        const float g1z = __bfloat162float(s1h[(size_t)src * 192 + 3 * lane + 2]);

        acc[0] = fmaf(w0a * g0a, sh0, acc[0]);
        acc[1] = fmaf(w0b * g0b, sh0, acc[1]);
        const float dotg = fmaf(g1x, sh1x, fmaf(g1y, sh1y, g1z * sh1z)) * RS3;
        acc[2] = fmaf(w3v, dotg, acc[2]);
        const float p1a = w1a * g0a, p1b = w1b * g0b;
        acc[3] = fmaf(p1a, sh1x, acc[3]);
        acc[4] = fmaf(p1a, sh1y, acc[4]);
        acc[5] = fmaf(p1a, sh1z, acc[5]);
        acc[6] = fmaf(p1b, sh1x, acc[6]);
        acc[7] = fmaf(p1b, sh1y, acc[7]);
        acc[8] = fmaf(p1b, sh1z, acc[8]);
        const float q = w2v * sh0;
        acc[9]  = fmaf(q, g1x, acc[9]);
        acc[10] = fmaf(q, g1y, acc[10]);
        acc[11] = fmaf(q, g1z, acc[11]);
    }

    // stage scaled r row + scaled receiver_input into LDS
    const float rattr = receiver_attr[p];
    const float rfac  = RSNEI * rattr;
    rr_s[wave][lane]               = acc[0]  * rfac;
    rr_s[wave][64 + lane]          = acc[1]  * rfac;
    rr_s[wave][128 + lane]         = acc[2]  * rfac;
    rr_s[wave][192 + 3 * lane]     = acc[3]  * rfac;
    rr_s[wave][192 + 3 * lane + 1] = acc[4]  * rfac;
    rr_s[wave][192 + 3 * lane + 2] = acc[5]  * rfac;
    rr_s[wave][384 + 3 * lane]     = acc[6]  * rfac;
    rr_s[wave][384 + 3 * lane + 1] = acc[7]  * rfac;
    rr_s[wave][384 + 3 * lane + 2] = acc[8]  * rfac;
    rr_s[wave][576 + 3 * lane]     = acc[9]  * rfac;
    rr_s[wave][576 + 3 * lane + 1] = acc[10] * rfac;
    rr_s[wave][576 + 3 * lane + 2] = acc[11] * rfac;
    for (int jj = lane; jj < DIM; jj += 64)
        rin_s[wave][jj] = receiver_input[(size_t)p * DIM + jj] * rattr;
    __syncthreads();

    // angle per receiver (8 lanes each, all in wave 0)
    if (tid < 32) {
        const int pw = tid >> 3, i0 = tid & 7;
        float a = 0.f;
        for (int u = i0; u < MID0; u += 8)
            a = fmaf(rr_s[pw][u], lin3_w[u], a);
        a += __shfl_xor(a, 1);
        a += __shfl_xor(a, 2);
        a += __shfl_xor(a, 4);
        if (i0 == 0) {
            a *= 0.1f * RS192;
            cs_s[pw] = __cosf(a);
            sn_s[pw] = __sinf(a);
        }
    }
    __syncthreads();

    // output: 320 columns x 4 receivers, weights reused across the 4
    for (int jj = tid; jj < DIM; jj += 256) {
        float asc[4] = {0.f, 0.f, 0.f, 0.f};
        float acv[4] = {0.f, 0.f, 0.f, 0.f};
        if (jj < MUL0) {
            for (int u = 0; u < MUL0; ++u) {
                const float w = sc_w0[u * MUL0 + jj];
                #pragma unroll
                for (int pp = 0; pp < 4; ++pp)
                    asc[pp] = fmaf(rin_s[pp][u], w, asc[pp]);
            }
            for (int u = 0; u < MID0; ++u) {
                const float w = lin2_w0[u * MUL0 + jj];
                #pragma unroll
                for (int pp = 0; pp < 4; ++pp)
                    acv[pp] = fmaf(rr_s[pp][u], w, acv[pp]);
            }
            #pragma unroll
            for (int pp = 0; pp < 4; ++pp)
                if (sel_s[pp])
                    out[(size_t)(blockIdx.x * 4 + pp) * DIM + jj] =
                        cs_s[pp] * asc[pp] * RS128 + sn_s[pp] * acv[pp] * RS192;
        } else {
            const int idx = jj - MUL0;
            const int v = idx / 3, m = idx - 3 * v;
            for (int u = 0; u < MUL1; ++u) {
                const float w = sc_w1[u * MUL1 + v];
                #pragma unroll
                for (int pp = 0; pp < 4; ++pp)
                    asc[pp] = fmaf(rin_s[pp][MUL0 + 3 * u + m], w, asc[pp]);
            }
            for (int u = 0; u < MID0; ++u) {
                const float w = lin2_w1[u * MUL1 + v];
                #pragma unroll
                for (int pp = 0; pp < 4; ++pp)
                    acv[pp] = fmaf(rr_s[pp][192 + 3 * u + m], w, acv[pp]);
            }
            #pragma unroll
            for (int pp = 0; pp < 4; ++pp)
                if (sel_s[pp])
                    out[(size_t)(blockIdx.x * 4 + pp) * DIM + jj] =
                        cs_s[pp] * asc[pp] * RS64 + sn_s[pp] * acv[pp] * RS192;
        }
    }
}

// ---------------------------------------------------------------------------
extern "C" void kernel_launch(void* const* d_in, const int* in_sizes, int n_in,
                              void* d_out, int out_size, void* d_ws, size_t ws_size,
                              hipStream_t stream)
{
    const float* sender_input   = (const float*)d_in[0];
    const float* sender_attr    = (const float*)d_in[1];
    const float* receiver_input = (const float*)d_in[2];
    const float* receiver_attr  = (const float*)d_in[3];
    const int*   edge_src       = (const int*)  d_in[4];
    const int*   edge_dst       = (const int*)  d_in[5];
    const float* edge_attr      = (const float*)d_in[6];
    const float* edge_scalars   = (const float*)d_in[7];
    const float* fc_w1          = (const float*)d_in[8];
    const float* fc_w2          = (const float*)d_in[9];
    const float* lin1_w0        = (const float*)d_in[10];
    const float* lin1_w1        = (const float*)d_in[11];
    const float* sc_w0          = (const float*)d_in[12];
    const float* sc_w1          = (const float*)d_in[13];
    const float* lin2_w0        = (const float*)d_in[14];
    const float* lin2_w1        = (const float*)d_in[15];
    const float* lin3_w         = (const float*)d_in[16];
    float* out = (float*)d_out;

    // ws layout (~54 MB, fits proven >= 64 MB):
    // wbuf [(C+OV)*384] bf16 | s0h [A*128] bf16 | s1h [A*192] bf16 |
    // counts [P] | head [P] | sorted [E]
    __hip_bfloat16* wbuf = (__hip_bfloat16*)d_ws;
    __hip_bfloat16* s0h = wbuf + (size_t)(C_CHUNK + OV) * WNUM;
    __hip_bfloat16* s1h = s0h + (size_t)A_N * MUL0;
    int* counts = (int*)(s1h + (size_t)A_N * 192);
    int* head   = counts + P_N;
    int* sorted = head + P_N;

    sender_kernel<<<A_N, 320, 0, stream>>>(sender_input, sender_attr,
                                           lin1_w0, lin1_w1, s0h, s1h);
    hipMemsetAsync(counts, 0, P_N * sizeof(int), stream);
    hist_kernel<<<(E_N + 255) / 256, 256, 0, stream>>>(edge_dst, counts);
    scan_kernel<<<1, 1024, 0, stream>>>(counts, head);
    scatter_kernel<<<(E_N + 255) / 256, 256, 0, stream>>>(edge_dst, head, sorted);

    for (int c = 0; c < NCHUNK; ++c) {
        const int cLo  = c * C_CHUNK;
        const int nPos = (E_N - cLo < C_CHUNK + OV) ? (E_N - cLo) : (C_CHUNK + OV);
        const int cHi  = (c == NCHUNK - 1) ? (E_N + 1) : (cLo + C_CHUNK);
        mlp_gemm_chunk_kernel<<<nPos / 32, 384, 0, stream>>>(
            sorted, edge_scalars, fc_w1, fc_w2, wbuf, cLo);
        recv_gather_kernel<<<P_N / 4, 256, 0, stream>>>(
            sorted, head, counts, edge_src, edge_attr, wbuf, s0h, s1h,
            receiver_input, receiver_attr, sc_w0, sc_w1, lin2_w0, lin2_w1,
            lin3_w, out, cLo, cHi);
    }
}

// Round 6
// 380.090 us; speedup vs baseline: 63.4592x; 1.4773x over previous
//
#include <hip/hip_runtime.h>
#include <hip/hip_bf16.h>
#include <math.h>

// Problem constants
#define A_N    2000
#define P_N    20000
#define E_N    200000
#define MUL0   128
#define MUL1   64
#define DIM    320     // MUL0 + 3*MUL1
#define NBASIS 10
#define FC_HID 100
#define WNUM   384     // 128+128+64+64
#define MID0   192     // MUL0 + MUL1
#define RDIM   768     // 128 + 64 + 384 + 192

// chunking of the sorted edge list (bf16 wbuf -> 3 chunks)
#define C_CHUNK 66688
#define OV      128            // > max edges per receiver (Poisson(10) max ~30)
#define NCHUNK  3

// scales
#define RS10   0.31622776601683794f   // 1/sqrt(10)
#define RS100  0.1f                   // 1/sqrt(100)
#define RS128  0.08838834764831845f   // 1/sqrt(128)
#define RS64   0.125f                 // 1/sqrt(64)
#define RS192  0.07216878364870323f   // 1/sqrt(192)
#define RS3    0.5773502691896258f    // 1/sqrt(3)
#define RSNEI  0.31622776601683794f   // 1/sqrt(10) neighbors

typedef __bf16 bf16x8 __attribute__((ext_vector_type(8)));
typedef float  f32x4  __attribute__((ext_vector_type(4)));

// ---------------------------------------------------------------------------
// Kernel 1: sender transform -> bf16 s0h/s1h (proven R3-R5)
// ---------------------------------------------------------------------------
__global__ __launch_bounds__(320) void sender_kernel(
    const float* __restrict__ sender_input, const float* __restrict__ sender_attr,
    const float* __restrict__ lin1_w0, const float* __restrict__ lin1_w1,
    __hip_bfloat16* __restrict__ s0h, __hip_bfloat16* __restrict__ s1h)
{
    __shared__ float sin_s[DIM];
    const int a = blockIdx.x;
    const int t = threadIdx.x;
    const float attr = sender_attr[a];
    sin_s[t] = sender_input[(size_t)a * DIM + t] * attr;
    __syncthreads();
    if (t < MUL0) {
        float acc = 0.f;
        for (int u = 0; u < MUL0; ++u)
            acc = fmaf(sin_s[u], lin1_w0[u * MUL0 + t], acc);
        s0h[(size_t)a * MUL0 + t] = __float2bfloat16(acc * RS128);
    } else {
        const int idx = t - MUL0;          // 0..191
        const int v = idx / 3, m = idx - 3 * v;
        float acc = 0.f;
        for (int u = 0; u < MUL1; ++u)
            acc = fmaf(sin_s[MUL0 + 3 * u + m], lin1_w1[u * MUL1 + v], acc);
        s1h[(size_t)a * 192 + idx] = __float2bfloat16(acc * RS64);
    }
}

// ---------------------------------------------------------------------------
// CSR build: histogram -> scan -> scatter   (proven R3-R5)
// ---------------------------------------------------------------------------
__global__ __launch_bounds__(256) void hist_kernel(
    const int* __restrict__ edge_dst, int* __restrict__ counts)
{
    const int e = blockIdx.x * 256 + threadIdx.x;
    if (e < E_N) atomicAdd(&counts[edge_dst[e]], 1);
}

__global__ __launch_bounds__(1024) void scan_kernel(
    const int* __restrict__ counts, int* __restrict__ head)
{
    __shared__ int part[1024];
    const int t = threadIdx.x;
    const int base = t * 20;
    int c[20];
    int s = 0;
    #pragma unroll
    for (int i = 0; i < 20; ++i) {
        const int p = base + i;
        c[i] = (p < P_N) ? counts[p] : 0;
        s += c[i];
    }
    part[t] = s;
    __syncthreads();
    for (int off = 1; off < 1024; off <<= 1) {
        const int v = (t >= off) ? part[t - off] : 0;
        __syncthreads();
        part[t] += v;
        __syncthreads();
    }
    int run = (t > 0) ? part[t - 1] : 0;   // exclusive prefix
    #pragma unroll
    for (int i = 0; i < 20; ++i) {
        const int p = base + i;
        if (p < P_N) { head[p] = run; run += c[i]; }
    }
}

__global__ __launch_bounds__(256) void scatter_kernel(
    const int* __restrict__ edge_dst, int* __restrict__ head,
    int* __restrict__ sorted)
{
    const int e = blockIdx.x * 256 + threadIdx.x;
    if (e < E_N) {
        const int pos = atomicAdd(&head[edge_dst[e]], 1);
        sorted[pos] = e;
    }
}

// ---------------------------------------------------------------------------
// pack_w2: fc_w2 (100x384 f32) -> bf16 fragment-ordered B buffer.
// Layout: frag (n-tile n, k-slice g): 64 lanes x 8 bf16 (16B per lane).
// Element i of lane l: k = g*32 + 8*(l>>4) + i, col = n*16 + (l&15).
// Zero-pad k in [100,128). RS100 folded in. 24*4*64*16B = 96 KB.
// ---------------------------------------------------------------------------
__global__ __launch_bounds__(256) void pack_w2_kernel(
    const float* __restrict__ fc_w2, __bf16* __restrict__ w2p)
{
    const int tid  = blockIdx.x * 256 + threadIdx.x;   // 0..6143
    const int lane = tid & 63;
    const int g    = (tid >> 6) & 3;
    const int n    = tid >> 8;
    const int col  = n * 16 + (lane & 15);
    const int kb   = g * 32 + 8 * (lane >> 4);
    bf16x8 v;
    #pragma unroll
    for (int i = 0; i < 8; ++i) {
        const int k = kb + i;
        v[i] = (__bf16)((k < FC_HID) ? fc_w2[k * WNUM + col] * RS100 : 0.f);
    }
    ((bf16x8*)w2p)[tid] = v;
}

// ---------------------------------------------------------------------------
// Kernel A (MFMA): MLP + weight GEMM over one chunk of the SORTED edge list.
// 256 threads = 4 waves, 64 edges/block. h (bf16, k-padded to 128) in LDS
// with XOR swizzle (e&7)<<3 to kill A-frag ds_read_b128 bank conflicts.
// Wave w owns n-tiles [6w, 6w+6); per n-tile: 4 m-tiles x 4 K-slice MFMAs.
// ---------------------------------------------------------------------------
__global__ __launch_bounds__(256) void mlp_gemm_chunk_kernel(
    const int* __restrict__ sorted,
    const float* __restrict__ edge_scalars,
    const float* __restrict__ fc_w1, const __bf16* __restrict__ w2p,
    __hip_bfloat16* __restrict__ wbuf, int cLo)
{
    __shared__ float  fc1s[NBASIS * FC_HID];   // 4 KB
    __shared__ float  es_s[64][NBASIS];        // 2.5 KB
    __shared__ __bf16 h_lds[64 * 128];         // 16 KB
    __shared__ int    eid_s[64];

    const int tid   = threadIdx.x;
    const int wave  = tid >> 6;
    const int lane  = tid & 63;
    const int pbase = blockIdx.x * 64;         // position within chunk

    if (tid < 64) eid_s[tid] = sorted[cLo + pbase + tid];
    for (int i = tid; i < NBASIS * FC_HID; i += 256) fc1s[i] = fc_w1[i];
    __syncthreads();

    for (int f = tid; f < 64 * NBASIS; f += 256) {
        const int e = f / NBASIS, i = f - e * NBASIS;
        es_s[e][i] = edge_scalars[(size_t)eid_s[e] * NBASIS + i];
    }
    __syncthreads();

    // h: thread t -> edge t>>2, k-range (t&3)*32..+31; silu; bf16 -> LDS
    {
        const int e  = tid >> 2;
        const int k0 = (tid & 3) * 32;
        float es[NBASIS];
        #pragma unroll
        for (int i = 0; i < NBASIS; ++i) es[i] = es_s[e][i];
        #pragma unroll
        for (int o = 0; o < 4; ++o) {
            bf16x8 hv;
            #pragma unroll
            for (int j = 0; j < 8; ++j) {
                const int k = k0 + o * 8 + j;
                float x = 0.f;
                if (k < FC_HID) {
                    #pragma unroll
                    for (int i = 0; i < NBASIS; ++i)
                        x = fmaf(es[i], fc1s[i * FC_HID + k], x);
                    x *= RS10;
                    x = x / (1.f + __expf(-x));   // silu
                }
                hv[j] = (__bf16)x;
            }
            const int idx = (e * 128 + k0 + o * 8) ^ ((e & 7) << 3);
            *(bf16x8*)&h_lds[idx] = hv;
        }
    }
    __syncthreads();

    // A frags: 4 m-tiles x 4 K-slices (row = lane&15, k-octet = lane>>4)
    bf16x8 a[4][4];
    const int arow = lane & 15, ag = lane >> 4;
    #pragma unroll
    for (int mt = 0; mt < 4; ++mt) {
        const int e = mt * 16 + arow;
        #pragma unroll
        for (int g = 0; g < 4; ++g) {
            const int idx = (e * 128 + g * 32 + ag * 8) ^ ((e & 7) << 3);
            a[mt][g] = *(const bf16x8*)&h_lds[idx];
        }
    }

    const bf16x8* w2v = (const bf16x8*)w2p;
    const int row0 = 4 * (lane >> 4), col = lane & 15;

    for (int nt = 0; nt < 6; ++nt) {
        const int ntile = wave * 6 + nt;
        bf16x8 b[4];
        #pragma unroll
        for (int g = 0; g < 4; ++g)
            b[g] = w2v[(ntile * 4 + g) * 64 + lane];
        #pragma unroll
        for (int mt = 0; mt < 4; ++mt) {
            f32x4 acc = {0.f, 0.f, 0.f, 0.f};
            #pragma unroll
            for (int g = 0; g < 4; ++g)
                acc = __builtin_amdgcn_mfma_f32_16x16x32_bf16(a[mt][g], b[g],
                                                              acc, 0, 0, 0);
            __hip_bfloat16* wr =
                wbuf + (size_t)(pbase + mt * 16 + row0) * WNUM + ntile * 16 + col;
            #pragma unroll
            for (int j = 0; j < 4; ++j)
                wr[(size_t)j * WNUM] = __float2bfloat16(acc[j]);
        }
    }
}

// ---------------------------------------------------------------------------
// Kernel B: gather + receiver finish, fused (proven R4/R5; wbuf bf16,
// RS100 already folded into wbuf values).
// ---------------------------------------------------------------------------
__global__ __launch_bounds__(256) void recv_gather_kernel(
    const int* __restrict__ sorted, const int* __restrict__ head,
    const int* __restrict__ counts,
    const int* __restrict__ edge_src, const float* __restrict__ edge_attr,
    const __hip_bfloat16* __restrict__ wbuf,
    const __hip_bfloat16* __restrict__ s0h, const __hip_bfloat16* __restrict__ s1h,
    const float* __restrict__ receiver_input, const float* __restrict__ receiver_attr,
    const float* __restrict__ sc_w0,  const float* __restrict__ sc_w1,
    const float* __restrict__ lin2_w0, const float* __restrict__ lin2_w1,
    const float* __restrict__ lin3_w,
    float* __restrict__ out, int cLo, int cHi)
{
    __shared__ float rr_s[4][RDIM];    // 12 KB   (scaled r rows)
    __shared__ float rin_s[4][DIM];    // 5 KB
    __shared__ float cs_s[4], sn_s[4];
    __shared__ int   sel_s[4];

    const int tid  = threadIdx.x;
    const int wave = tid >> 6;
    const int lane = tid & 63;
    const int p = blockIdx.x * 4 + wave;

    const int cnt   = counts[p];
    const int start = head[p] - cnt;               // head = segment end
    const int sel   = (start >= cLo) & (start < cHi);

    if (lane == 0) sel_s[wave] = sel;
    __syncthreads();
    if ((sel_s[0] | sel_s[1] | sel_s[2] | sel_s[3]) == 0) return;  // uniform

    const int cntEff = sel ? cnt : 0;

    float acc[12];
    #pragma unroll
    for (int i = 0; i < 12; ++i) acc[i] = 0.f;

    for (int i = 0; i < cntEff; ++i) {
        const int pos = start + i;
        const int eid = sorted[pos];
        const __hip_bfloat16* wr = wbuf + (size_t)(pos - cLo) * WNUM;
        const float w0a = __bfloat162float(wr[lane]);
        const float w0b = __bfloat162float(wr[64 + lane]);
        const float w1a = __bfloat162float(wr[128 + lane]);
        const float w1b = __bfloat162float(wr[192 + lane]);
        const float w2v = __bfloat162float(wr[256 + lane]);
        const float w3v = __bfloat162float(wr[320 + lane]);

        const int src = edge_src[eid];
        const float4 ea = ((const float4*)edge_attr)[eid];
        const float sh0 = ea.x, sh1x = ea.y, sh1y = ea.z, sh1z = ea.w;

        const float g0a = __bfloat162float(s0h[(size_t)src * MUL0 + lane]);
        const float g0b = __bfloat162float(s0h[(size_t)src * MUL0 + 64 + lane]);
        const float g1x = __bfloat162float(s1h[(size_t)src * 192 + 3 * lane + 0]);
        const float g1y = __bfloat162float(s1h[(size_t)src * 192 + 3 * lane + 1]);
        const float g1z = __bfloat162float(s1h[(size_t)src * 192 + 3 * lane + 2]);

        acc[0] = fmaf(w0a * g0a, sh0, acc[0]);
        acc[1] = fmaf(w0b * g0b, sh0, acc[1]);
        const float dotg = fmaf(g1x, sh1x, fmaf(g1y, sh1y, g1z * sh1z)) * RS3;
        acc[2] = fmaf(w3v, dotg, acc[2]);
        const float p1a = w1a * g0a, p1b = w1b * g0b;
        acc[3] = fmaf(p1a, sh1x, acc[3]);
        acc[4] = fmaf(p1a, sh1y, acc[4]);
        acc[5] = fmaf(p1a, sh1z, acc[5]);
        acc[6] = fmaf(p1b, sh1x, acc[6]);
        acc[7] = fmaf(p1b, sh1y, acc[7]);
        acc[8] = fmaf(p1b, sh1z, acc[8]);
        const float q = w2v * sh0;
        acc[9]  = fmaf(q, g1x, acc[9]);
        acc[10] = fmaf(q, g1y, acc[10]);
        acc[11] = fmaf(q, g1z, acc[11]);
    }

    // stage scaled r row + scaled receiver_input into LDS
    const float rattr = receiver_attr[p];
    const float rfac  = RSNEI * rattr;
    rr_s[wave][lane]               = acc[0]  * rfac;
    rr_s[wave][64 + lane]          = acc[1]  * rfac;
    rr_s[wave][128 + lane]         = acc[2]  * rfac;
    rr_s[wave][192 + 3 * lane]     = acc[3]  * rfac;
    rr_s[wave][192 + 3 * lane + 1] = acc[4]  * rfac;
    rr_s[wave][192 + 3 * lane + 2] = acc[5]  * rfac;
    rr_s[wave][384 + 3 * lane]     = acc[6]  * rfac;
    rr_s[wave][384 + 3 * lane + 1] = acc[7]  * rfac;
    rr_s[wave][384 + 3 * lane + 2] = acc[8]  * rfac;
    rr_s[wave][576 + 3 * lane]     = acc[9]  * rfac;
    rr_s[wave][576 + 3 * lane + 1] = acc[10] * rfac;
    rr_s[wave][576 + 3 * lane + 2] = acc[11] * rfac;
    for (int jj = lane; jj < DIM; jj += 64)
        rin_s[wave][jj] = receiver_input[(size_t)p * DIM + jj] * rattr;
    __syncthreads();

    // angle per receiver (8 lanes each, all in wave 0)
    if (tid < 32) {
        const int pw = tid >> 3, i0 = tid & 7;
        float a = 0.f;
        for (int u = i0; u < MID0; u += 8)
            a = fmaf(rr_s[pw][u], lin3_w[u], a);
        a += __shfl_xor(a, 1);
        a += __shfl_xor(a, 2);
        a += __shfl_xor(a, 4);
        if (i0 == 0) {
            a *= 0.1f * RS192;
            cs_s[pw] = __cosf(a);
            sn_s[pw] = __sinf(a);
        }
    }
    __syncthreads();

    // output: 320 columns x 4 receivers, weights reused across the 4
    for (int jj = tid; jj < DIM; jj += 256) {
        float asc[4] = {0.f, 0.f, 0.f, 0.f};
        float acv[4] = {0.f, 0.f, 0.f, 0.f};
        if (jj < MUL0) {
            for (int u = 0; u < MUL0; ++u) {
                const float w = sc_w0[u * MUL0 + jj];
                #pragma unroll
                for (int pp = 0; pp < 4; ++pp)
                    asc[pp] = fmaf(rin_s[pp][u], w, asc[pp]);
            }
            for (int u = 0; u < MID0; ++u) {
                const float w = lin2_w0[u * MUL0 + jj];
                #pragma unroll
                for (int pp = 0; pp < 4; ++pp)
                    acv[pp] = fmaf(rr_s[pp][u], w, acv[pp]);
            }
            #pragma unroll
            for (int pp = 0; pp < 4; ++pp)
                if (sel_s[pp])
                    out[(size_t)(blockIdx.x * 4 + pp) * DIM + jj] =
                        cs_s[pp] * asc[pp] * RS128 + sn_s[pp] * acv[pp] * RS192;
        } else {
            const int idx = jj - MUL0;
            const int v = idx / 3, m = idx - 3 * v;
            for (int u = 0; u < MUL1; ++u) {
                const float w = sc_w1[u * MUL1 + v];
                #pragma unroll
                for (int pp = 0; pp < 4; ++pp)
                    asc[pp] = fmaf(rin_s[pp][MUL0 + 3 * u + m], w, asc[pp]);
            }
            for (int u = 0; u < MID0; ++u) {
                const float w = lin2_w1[u * MUL1 + v];
                #pragma unroll
                for (int pp = 0; pp < 4; ++pp)
                    acv[pp] = fmaf(rr_s[pp][192 + 3 * u + m], w, acv[pp]);
            }
            #pragma unroll
            for (int pp = 0; pp < 4; ++pp)
                if (sel_s[pp])
                    out[(size_t)(blockIdx.x * 4 + pp) * DIM + jj] =
                        cs_s[pp] * asc[pp] * RS64 + sn_s[pp] * acv[pp] * RS192;
        }
    }
}

// ---------------------------------------------------------------------------
extern "C" void kernel_launch(void* const* d_in, const int* in_sizes, int n_in,
                              void* d_out, int out_size, void* d_ws, size_t ws_size,
                              hipStream_t stream)
{
    const float* sender_input   = (const float*)d_in[0];
    const float* sender_attr    = (const float*)d_in[1];
    const float* receiver_input = (const float*)d_in[2];
    const float* receiver_attr  = (const float*)d_in[3];
    const int*   edge_src       = (const int*)  d_in[4];
    const int*   edge_dst       = (const int*)  d_in[5];
    const float* edge_attr      = (const float*)d_in[6];
    const float* edge_scalars   = (const float*)d_in[7];
    const float* fc_w1          = (const float*)d_in[8];
    const float* fc_w2          = (const float*)d_in[9];
    const float* lin1_w0        = (const float*)d_in[10];
    const float* lin1_w1        = (const float*)d_in[11];
    const float* sc_w0          = (const float*)d_in[12];
    const float* sc_w1          = (const float*)d_in[13];
    const float* lin2_w0        = (const float*)d_in[14];
    const float* lin2_w1        = (const float*)d_in[15];
    const float* lin3_w         = (const float*)d_in[16];
    float* out = (float*)d_out;

    // ws layout (~54.2 MB, fits proven >= 64 MB):
    // wbuf [(C+OV)*384] bf16 | s0h [A*128] bf16 | s1h [A*192] bf16 |
    // w2pack [24*4*64*8] bf16 | counts [P] | head [P] | sorted [E]
    __hip_bfloat16* wbuf = (__hip_bfloat16*)d_ws;
    __hip_bfloat16* s0h  = wbuf + (size_t)(C_CHUNK + OV) * WNUM;
    __hip_bfloat16* s1h  = s0h + (size_t)A_N * MUL0;
    __bf16* w2pack       = (__bf16*)(s1h + (size_t)A_N * 192);
    int* counts = (int*)(w2pack + 24 * 4 * 64 * 8);
    int* head   = counts + P_N;
    int* sorted = head + P_N;

    sender_kernel<<<A_N, 320, 0, stream>>>(sender_input, sender_attr,
                                           lin1_w0, lin1_w1, s0h, s1h);
    pack_w2_kernel<<<24, 256, 0, stream>>>(fc_w2, w2pack);
    hipMemsetAsync(counts, 0, P_N * sizeof(int), stream);
    hist_kernel<<<(E_N + 255) / 256, 256, 0, stream>>>(edge_dst, counts);
    scan_kernel<<<1, 1024, 0, stream>>>(counts, head);
    scatter_kernel<<<(E_N + 255) / 256, 256, 0, stream>>>(edge_dst, head, sorted);

    for (int c = 0; c < NCHUNK; ++c) {
        const int cLo  = c * C_CHUNK;
        const int nPos = (E_N - cLo < C_CHUNK + OV) ? (E_N - cLo) : (C_CHUNK + OV);
        const int cHi  = (c == NCHUNK - 1) ? (E_N + 1) : (cLo + C_CHUNK);
        mlp_gemm_chunk_kernel<<<nPos / 64, 256, 0, stream>>>(
            sorted, edge_scalars, fc_w1, w2pack, wbuf, cLo);
        recv_gather_kernel<<<P_N / 4, 256, 0, stream>>>(
            sorted, head, counts, edge_src, edge_attr, wbuf, s0h, s1h,
            receiver_input, receiver_attr, sc_w0, sc_w1, lin2_w0, lin2_w1,
            lin3_w, out, cLo, cHi);
    }
}